// Round 4
// baseline (421.755 us; speedup 1.0000x reference)
//
#include <hip/hip_runtime.h>
#include <math.h>

// Problem constants (SpiralDeblock)
#define B      16
#define N_IN   7000
#define N_OUT  28000
#define C      64          // C_IN == C_OUT == 64
#define S      9
#define NNZ    (3 * N_OUT) // 84000
#define F      (S * C)     // 576
#define KB     (F / 32)    // 18 k-blocks of 32 for mfma 16x16x32

#define MT     110         // m-tiles in spiral_mfma: ceil(28000/256)
#define PBLK   7000        // blocks per batch in pool_kernel (4 rows each)

typedef short bf16x8 __attribute__((ext_vector_type(8)));  // 8 bf16 = 4 VGPRs
typedef float f32x4  __attribute__((ext_vector_type(4)));

// fp32 -> bf16 round-to-nearest-even (bit pattern as ushort)
static __device__ __forceinline__ unsigned short f2bf(float f) {
    unsigned u = __float_as_uint(f);
    u += 0x7fffu + ((u >> 16) & 1u);
    return (unsigned short)(u >> 16);
}

// ---------------------------------------------------------------------------
// CSR build: histogram -> exclusive scan -> placement.
// ---------------------------------------------------------------------------
__global__ void hist_kernel(const int* __restrict__ row, int* __restrict__ cnt) {
    int i = blockIdx.x * 256 + threadIdx.x;
    if (i < NNZ) atomicAdd(&cnt[row[i]], 1);
}

// 1024 threads; thread t owns rows [t*28, t*28+28) (t<1000; 1000*28==28000).
// Sequential per-thread partials + single 1024-wide LDS scan.
__global__ void scan_kernel(const int* __restrict__ cnt,
                            int* __restrict__ offs, int* __restrict__ cursor) {
    __shared__ int tmp[1024];
    const int t = threadIdx.x;
    const int base = t * 28;
    const bool live = (t < 1000);

    int c[28];
    int partial = 0;
    if (live) {
        #pragma unroll
        for (int j = 0; j < 28; ++j) { c[j] = cnt[base + j]; partial += c[j]; }
    }
    tmp[t] = partial;
    __syncthreads();
    #pragma unroll
    for (int off = 1; off < 1024; off <<= 1) {
        int v = (t >= off) ? tmp[t - off] : 0;
        __syncthreads();
        tmp[t] += v;
        __syncthreads();
    }
    if (live) {
        int run = tmp[t] - partial;   // exclusive prefix
        #pragma unroll
        for (int j = 0; j < 28; ++j) {
            offs[base + j]   = run;
            cursor[base + j] = run;
            run += c[j];
        }
        if (t == 999) offs[N_OUT] = run;
    }
}

__global__ void place_kernel(const int* __restrict__ row, const int* __restrict__ col,
                             const float* __restrict__ values,
                             int* __restrict__ cursor,
                             int* __restrict__ ecol, float* __restrict__ eval) {
    int i = blockIdx.x * 256 + threadIdx.x;
    if (i < NNZ) {
        int pos = atomicAdd(&cursor[row[i]], 1);
        ecol[pos] = col[i];
        eval[pos] = values[i];
    }
}

// ---------------------------------------------------------------------------
// Pooling: pooled_bf16[b, r, c] = sum_e x[b, ecol[e], c] * eval[e]  (e in row r)
// XCD-pinned: linear block L -> batch b with b%8 == L%8 (XCD = L%8 heuristic),
// so each XCD's co-resident blocks share one batch; that batch's x slice
// (1.79 MB) stays L2-resident. Block = 4 waves, one output row per wave.
// ---------------------------------------------------------------------------
__global__ void pool_kernel(const float* __restrict__ x,
                            const int*   __restrict__ ecol,
                            const float* __restrict__ eval,
                            const int*   __restrict__ offs,
                            unsigned short* __restrict__ pooled) {
    const int lane = threadIdx.x & 63;
    const int wave = threadIdx.x >> 6;
    const int L    = blockIdx.x;            // 0 .. 16*PBLK-1

    int b, rblk;
    if (L < 8 * PBLK) { b = L & 7;            rblk = L >> 3; }
    else              { b = 8 + ((L - 8 * PBLK) & 7); rblk = (L - 8 * PBLK) >> 3; }
    const int r = rblk * 4 + wave;

    const int start = offs[r], end = offs[r + 1];
    const float* xb = x + (size_t)b * N_IN * C;

    float acc = 0.f;
    for (int e = start; e < end; ++e) {
        acc = fmaf(xb[(size_t)ecol[e] * C + lane], eval[e], acc);
    }
    pooled[((size_t)b * N_OUT + r) * C + lane] = f2bf(acc);
}

// ---------------------------------------------------------------------------
// Pack weight (576x64 fp32, row-major [f][o]) into MFMA B-fragment lane order:
// packedW[((kb*4 + nt)*64 + lane)*8 + j] = bf16( W[(kb*32 + quad*8 + j)*64 + nt*16 + lm] )
// ---------------------------------------------------------------------------
__global__ void packw_kernel(const float* __restrict__ w, unsigned short* __restrict__ pw) {
    const int kb   = blockIdx.x;        // 0..17
    const int nt   = threadIdx.x >> 6;  // 0..3
    const int lane = threadIdx.x & 63;
    const int lm   = lane & 15;
    const int quad = lane >> 4;

    unsigned short v[8];
    #pragma unroll
    for (int j = 0; j < 8; ++j) {
        const int k = kb * 32 + quad * 8 + j;
        const int n = nt * 16 + lm;
        v[j] = f2bf(w[(size_t)k * C + n]);
    }
    unsigned short* dst = pw + ((size_t)(kb * 4 + nt) * 64 + lane) * 8;
    #pragma unroll
    for (int j = 0; j < 8; ++j) dst[j] = v[j];
}

// ---------------------------------------------------------------------------
// Gathered GEMM via MFMA 16x16x32 bf16, XCD-pinned by batch.
// Linear block L -> (b, mtile) with b%8 == L%8, so each XCD's co-resident
// blocks gather within one batch's pooled slice (3.58 MB < 4 MB L2/XCD).
// Wave computes 64 rows x 64 cols (acc[t][nt]).
// A-frag: lane holds A[m=lane&15][k=quad*8+j] -> one 16 B load from the
//         gathered pooled row (contiguous bf16 channels), no LDS.
// B-frag: coalesced 16 B load from packedW (72 KB, L2-resident).
// C/D:    col = lane&15, row = quad*4 + reg.
// ---------------------------------------------------------------------------
__global__ __launch_bounds__(256, 3)
void spiral_mfma(const unsigned short* __restrict__ pooled,
                 const bf16x8*         __restrict__ packedW,
                 const int*            __restrict__ sp,
                 const float*          __restrict__ bias,
                 float*                __restrict__ out) {
    const int L = blockIdx.x;               // 0 .. 16*MT-1
    int b, mtile;
    if (L < 8 * MT) { b = L & 7;                mtile = L >> 3; }
    else            { b = 8 + ((L - 8 * MT) & 7); mtile = (L - 8 * MT) >> 3; }

    const int wave = threadIdx.x >> 6;
    const int lane = threadIdx.x & 63;
    const int lm   = lane & 15;
    const int quad = lane >> 4;
    const int m_base = mtile * 256 + wave * 64;

    // Lane i pre-loads sp[m_base+i, 0..8]; distributed to tiles via shfl.
    int spv[S];
    {
        int r = m_base + lane;
        if (r >= N_OUT) r = N_OUT - 1;
        #pragma unroll
        for (int s = 0; s < S; ++s) spv[s] = sp[r * S + s];
    }

    const unsigned short* poolb = pooled + (size_t)b * N_OUT * C;

    f32x4 acc[4][4];
    #pragma unroll
    for (int t = 0; t < 4; ++t)
        #pragma unroll
        for (int nt = 0; nt < 4; ++nt)
            acc[t][nt] = (f32x4){0.f, 0.f, 0.f, 0.f};

    #pragma unroll
    for (int s = 0; s < S; ++s) {
        int rowi[4];
        #pragma unroll
        for (int t = 0; t < 4; ++t)
            rowi[t] = __shfl(spv[s], t * 16 + lm, 64);

        #pragma unroll
        for (int half = 0; half < 2; ++half) {
            const int kb = s * 2 + half;
            const int c0 = half * 32 + quad * 8;

            bf16x8 a[4];
            #pragma unroll
            for (int t = 0; t < 4; ++t)
                a[t] = *(const bf16x8*)(poolb + (size_t)rowi[t] * C + c0);

            #pragma unroll
            for (int nt = 0; nt < 4; ++nt) {
                const bf16x8 bf = packedW[(kb * 4 + nt) * 64 + lane];
                #pragma unroll
                for (int t = 0; t < 4; ++t)
                    acc[t][nt] = __builtin_amdgcn_mfma_f32_16x16x32_bf16(
                        a[t], bf, acc[t][nt], 0, 0, 0);
            }
        }
    }

    // Epilogue: bias + ELU + store.
    #pragma unroll
    for (int nt = 0; nt < 4; ++nt) {
        const int n = nt * 16 + lm;
        const float bs = bias[n];
        #pragma unroll
        for (int t = 0; t < 4; ++t) {
            #pragma unroll
            for (int reg = 0; reg < 4; ++reg) {
                const int r = m_base + t * 16 + quad * 4 + reg;
                if (r < N_OUT) {
                    float v = acc[t][nt][reg] + bs;
                    v = v > 0.f ? v : expm1f(v);
                    out[((size_t)b * N_OUT + r) * C + n] = v;
                }
            }
        }
    }
}

// ---------------------------------------------------------------------------
// Launch.
// Inputs: 0:x 1:values 2:weight 3:bias 4:row 5:col 6:spiral_indices
// Workspace ~58.4 MB (R0 proved ws >= 114.7 MB).
// ---------------------------------------------------------------------------
extern "C" void kernel_launch(void* const* d_in, const int* in_sizes, int n_in,
                              void* d_out, int out_size, void* d_ws, size_t ws_size,
                              hipStream_t stream) {
    const float* x      = (const float*)d_in[0];
    const float* values = (const float*)d_in[1];
    const float* weight = (const float*)d_in[2];
    const float* bias   = (const float*)d_in[3];
    const int*   row    = (const int*)d_in[4];
    const int*   col    = (const int*)d_in[5];
    const int*   sp     = (const int*)d_in[6];
    float*       out    = (float*)d_out;

    char* ws = (char*)d_ws;
    size_t off = 0;
    unsigned short* pooled  = (unsigned short*)(ws + off); off += (size_t)B * N_OUT * C * 2;      // 57,344,000
    unsigned short* packedW = (unsigned short*)(ws + off); off += (size_t)KB * 4 * 64 * 8 * 2;    // 73,728
    int*   offs   = (int*)(ws + off); off += ((size_t)(N_OUT + 1) * 4 + 124) / 128 * 128;
    int*   cursor = (int*)(ws + off); off += (size_t)N_OUT * 4 + 128;
    int*   cnt    = (int*)(ws + off); off += (size_t)N_OUT * 4 + 128;
    int*   ecol   = (int*)(ws + off); off += (size_t)NNZ * 4;
    float* eval   = (float*)(ws + off); off += (size_t)NNZ * 4;

    // CSR build (cnt must start at zero; ws is poisoned each call).
    (void)hipMemsetAsync(cnt, 0, (size_t)N_OUT * 4, stream);
    hist_kernel <<<(NNZ + 255) / 256, 256, 0, stream>>>(row, cnt);
    scan_kernel <<<1, 1024, 0, stream>>>(cnt, offs, cursor);
    place_kernel<<<(NNZ + 255) / 256, 256, 0, stream>>>(row, col, values, cursor, ecol, eval);

    // Pack weight into MFMA B-fragment order (independent of CSR chain).
    packw_kernel<<<KB, 256, 0, stream>>>(weight, packedW);

    // Pool into bf16 (XCD-pinned by batch).
    pool_kernel<<<B * PBLK, 256, 0, stream>>>(x, ecol, eval, offs, pooled);

    // Gathered GEMM + bias + ELU (XCD-pinned by batch).
    spiral_mfma<<<B * MT, 256, 0, stream>>>(pooled,
        reinterpret_cast<const bf16x8*>(packedW), sp, bias, out);
}

// Round 5
// 327.094 us; speedup vs baseline: 1.2894x; 1.2894x over previous
//
#include <hip/hip_runtime.h>
#include <math.h>

// Problem constants (SpiralDeblock)
#define B      16
#define N_IN   7000
#define N_OUT  28000
#define C      64          // C_IN == C_OUT == 64
#define S      9
#define NNZ    (3 * N_OUT) // 84000
#define F      (S * C)     // 576
#define KB     (F / 32)    // 18 k-blocks of 32 for mfma 16x16x32

#define MT     110         // m-tiles in spiral_mfma: ceil(28000/256)

typedef short bf16x8 __attribute__((ext_vector_type(8)));  // 8 bf16 = 4 VGPRs
typedef float f32x4  __attribute__((ext_vector_type(4)));

// fp32 -> bf16 round-to-nearest-even (bit pattern as ushort)
static __device__ __forceinline__ unsigned short f2bf(float f) {
    unsigned u = __float_as_uint(f);
    u += 0x7fffu + ((u >> 16) & 1u);
    return (unsigned short)(u >> 16);
}

// ---------------------------------------------------------------------------
// CSR build: histogram -> exclusive scan -> placement.
// ---------------------------------------------------------------------------
__global__ void hist_kernel(const int* __restrict__ row, int* __restrict__ cnt) {
    int i = blockIdx.x * 256 + threadIdx.x;
    if (i < NNZ) atomicAdd(&cnt[row[i]], 1);
}

// 1024 threads; thread t owns rows [t*28, t*28+28) (t<1000; 1000*28==28000).
// Sequential per-thread partials + single 1024-wide LDS scan.
__global__ void scan_kernel(const int* __restrict__ cnt,
                            int* __restrict__ offs, int* __restrict__ cursor) {
    __shared__ int tmp[1024];
    const int t = threadIdx.x;
    const int base = t * 28;
    const bool live = (t < 1000);

    int c[28];
    int partial = 0;
    if (live) {
        #pragma unroll
        for (int j = 0; j < 28; ++j) { c[j] = cnt[base + j]; partial += c[j]; }
    }
    tmp[t] = partial;
    __syncthreads();
    #pragma unroll
    for (int off = 1; off < 1024; off <<= 1) {
        int v = (t >= off) ? tmp[t - off] : 0;
        __syncthreads();
        tmp[t] += v;
        __syncthreads();
    }
    if (live) {
        int run = tmp[t] - partial;   // exclusive prefix
        #pragma unroll
        for (int j = 0; j < 28; ++j) {
            offs[base + j]   = run;
            cursor[base + j] = run;
            run += c[j];
        }
        if (t == 999) offs[N_OUT] = run;
    }
}

__global__ void place_kernel(const int* __restrict__ row, const int* __restrict__ col,
                             const float* __restrict__ values,
                             int* __restrict__ cursor,
                             int* __restrict__ ecol, float* __restrict__ eval) {
    int i = blockIdx.x * 256 + threadIdx.x;
    if (i < NNZ) {
        int pos = atomicAdd(&cursor[row[i]], 1);
        ecol[pos] = col[i];
        eval[pos] = values[i];
    }
}

// ---------------------------------------------------------------------------
// Pooling: pooled_bf16[b, r, c] = sum_e x[b, ecol[e], c] * eval[e]  (e in row r)
// 7000 blocks x 4 waves; wave owns one output row r for ALL 16 batches
// (ecol/eval read once per edge per wave). Lane split: group g = lane>>4
// (4 groups of 16), sublane sl = lane&15; lane loads float4 = channels
// sl*4..sl*4+3; group g handles batches g*4..g*4+3 -> 4 independent float4
// gathers per edge per lane (good MLP), acc[4] x float4 in regs.
// ---------------------------------------------------------------------------
__global__ void pool_kernel(const float* __restrict__ x,
                            const int*   __restrict__ ecol,
                            const float* __restrict__ eval,
                            const int*   __restrict__ offs,
                            unsigned short* __restrict__ pooled) {
    const int lane = threadIdx.x & 63;
    const int wave = threadIdx.x >> 6;
    const int r    = blockIdx.x * 4 + wave;   // 7000 blocks * 4 == 28000
    const int g    = lane >> 4;
    const int sl   = lane & 15;

    const int start = offs[r], end = offs[r + 1];

    float4 acc[4];
    #pragma unroll
    for (int j = 0; j < 4; ++j) acc[j] = make_float4(0.f, 0.f, 0.f, 0.f);

    for (int e = start; e < end; ++e) {
        const int   cl = ecol[e];
        const float v  = eval[e];
        const float* basep = x + (size_t)cl * C + sl * 4;
        #pragma unroll
        for (int j = 0; j < 4; ++j) {
            const float4 xv = *(const float4*)(basep + (size_t)(g * 4 + j) * N_IN * C);
            acc[j].x = fmaf(xv.x, v, acc[j].x);
            acc[j].y = fmaf(xv.y, v, acc[j].y);
            acc[j].z = fmaf(xv.z, v, acc[j].z);
            acc[j].w = fmaf(xv.w, v, acc[j].w);
        }
    }
    #pragma unroll
    for (int j = 0; j < 4; ++j) {
        const int b = g * 4 + j;
        ushort4 o;
        o.x = f2bf(acc[j].x); o.y = f2bf(acc[j].y);
        o.z = f2bf(acc[j].z); o.w = f2bf(acc[j].w);
        *(ushort4*)(pooled + ((size_t)b * N_OUT + r) * C + sl * 4) = o;
    }
}

// ---------------------------------------------------------------------------
// Pack weight (576x64 fp32, row-major [f][o]) into MFMA B-fragment lane order:
// packedW[((kb*4 + nt)*64 + lane)*8 + j] = bf16( W[(kb*32 + quad*8 + j)*64 + nt*16 + lm] )
// ---------------------------------------------------------------------------
__global__ void packw_kernel(const float* __restrict__ w, unsigned short* __restrict__ pw) {
    const int kb   = blockIdx.x;        // 0..17
    const int nt   = threadIdx.x >> 6;  // 0..3
    const int lane = threadIdx.x & 63;
    const int lm   = lane & 15;
    const int quad = lane >> 4;

    unsigned short v[8];
    #pragma unroll
    for (int j = 0; j < 8; ++j) {
        const int k = kb * 32 + quad * 8 + j;
        const int n = nt * 16 + lm;
        v[j] = f2bf(w[(size_t)k * C + n]);
    }
    unsigned short* dst = pw + ((size_t)(kb * 4 + nt) * 64 + lane) * 8;
    #pragma unroll
    for (int j = 0; j < 8; ++j) dst[j] = v[j];
}

// ---------------------------------------------------------------------------
// Gathered GEMM via MFMA 16x16x32 bf16, XCD-pinned by batch (b%8 == L%8:
// per-XCD pooled slice 3.58 MB < 4 MB L2 -- R4 measured FETCH 218->77 MB).
// Software-pipelined over s: prefetch s+1's 8 A-frags + 8 B-frags before
// issuing s's 16 MFMAs (explicit double buffer; ~16 loads in flight).
// Wave computes 64 rows x 64 cols (acc[t][nt], 64 AGPRs).
// A-frag: lane holds A[m=lane&15][k=quad*8+j] -> one 16 B load from the
//         gathered pooled row (contiguous bf16 channels), no LDS.
// B-frag: coalesced 16 B load from packedW (72 KB, L2-resident).
// C/D:    col = lane&15, row = quad*4 + reg.
// ---------------------------------------------------------------------------
__global__ __launch_bounds__(256, 2)
void spiral_mfma(const unsigned short* __restrict__ pooled,
                 const bf16x8*         __restrict__ packedW,
                 const int*            __restrict__ sp,
                 const float*          __restrict__ bias,
                 float*                __restrict__ out) {
    const int L = blockIdx.x;               // 0 .. 16*MT-1
    int b, mtile;
    if (L < 8 * MT) { b = L & 7;                mtile = L >> 3; }
    else            { b = 8 + ((L - 8 * MT) & 7); mtile = (L - 8 * MT) >> 3; }

    const int wave = threadIdx.x >> 6;
    const int lane = threadIdx.x & 63;
    const int lm   = lane & 15;
    const int quad = lane >> 4;
    const int m_base = mtile * 256 + wave * 64;

    // Lane i pre-loads sp[m_base+i, 0..8]; distributed to tiles via shfl.
    int spv[S];
    {
        int r = m_base + lane;
        if (r >= N_OUT) r = N_OUT - 1;
        #pragma unroll
        for (int s = 0; s < S; ++s) spv[s] = sp[r * S + s];
    }

    const unsigned short* poolb = pooled + (size_t)b * N_OUT * C;

    f32x4 acc[4][4];
    #pragma unroll
    for (int t = 0; t < 4; ++t)
        #pragma unroll
        for (int nt = 0; nt < 4; ++nt)
            acc[t][nt] = (f32x4){0.f, 0.f, 0.f, 0.f};

    // Pipeline buffers (explicit double buffer, indexed by s&1 -- constant
    // after full unroll).
    int    rowi[2][4];
    bf16x8 abuf[2][2][4];   // [buf][half][t]
    bf16x8 bbuf[2][2][4];   // [buf][half][nt]

    // Prologue: s = 0.
    #pragma unroll
    for (int t = 0; t < 4; ++t)
        rowi[0][t] = __shfl(spv[0], t * 16 + lm, 64);
    #pragma unroll
    for (int half = 0; half < 2; ++half) {
        const int c0 = half * 32 + quad * 8;
        #pragma unroll
        for (int t = 0; t < 4; ++t)
            abuf[0][half][t] = *(const bf16x8*)(poolb + (size_t)rowi[0][t] * C + c0);
        #pragma unroll
        for (int nt = 0; nt < 4; ++nt)
            bbuf[0][half][nt] = packedW[(half * 4 + nt) * 64 + lane];
    }

    #pragma unroll
    for (int s = 0; s < S; ++s) {
        const int cur = s & 1, nxt = cur ^ 1;

        // Prefetch s+1 before consuming s.
        if (s + 1 < S) {
            #pragma unroll
            for (int t = 0; t < 4; ++t)
                rowi[nxt][t] = __shfl(spv[s + 1], t * 16 + lm, 64);
            #pragma unroll
            for (int half = 0; half < 2; ++half) {
                const int c0 = half * 32 + quad * 8;
                #pragma unroll
                for (int t = 0; t < 4; ++t)
                    abuf[nxt][half][t] =
                        *(const bf16x8*)(poolb + (size_t)rowi[nxt][t] * C + c0);
                #pragma unroll
                for (int nt = 0; nt < 4; ++nt)
                    bbuf[nxt][half][nt] =
                        packedW[(((s + 1) * 2 + half) * 4 + nt) * 64 + lane];
            }
        }

        #pragma unroll
        for (int half = 0; half < 2; ++half)
            #pragma unroll
            for (int nt = 0; nt < 4; ++nt)
                #pragma unroll
                for (int t = 0; t < 4; ++t)
                    acc[t][nt] = __builtin_amdgcn_mfma_f32_16x16x32_bf16(
                        abuf[cur][half][t], bbuf[cur][half][nt], acc[t][nt], 0, 0, 0);
    }

    // Epilogue: bias + ELU + store. __expf -> v_exp_f32 (fast HW transcendental).
    #pragma unroll
    for (int nt = 0; nt < 4; ++nt) {
        const int n = nt * 16 + lm;
        const float bs = bias[n];
        #pragma unroll
        for (int t = 0; t < 4; ++t) {
            #pragma unroll
            for (int reg = 0; reg < 4; ++reg) {
                const int r = m_base + t * 16 + quad * 4 + reg;
                if (r < N_OUT) {
                    float v = acc[t][nt][reg] + bs;
                    v = v > 0.f ? v : (__expf(v) - 1.0f);
                    out[((size_t)b * N_OUT + r) * C + n] = v;
                }
            }
        }
    }
}

// ---------------------------------------------------------------------------
// Launch.
// Inputs: 0:x 1:values 2:weight 3:bias 4:row 5:col 6:spiral_indices
// Workspace ~58.4 MB (R0 proved ws >= 114.7 MB).
// ---------------------------------------------------------------------------
extern "C" void kernel_launch(void* const* d_in, const int* in_sizes, int n_in,
                              void* d_out, int out_size, void* d_ws, size_t ws_size,
                              hipStream_t stream) {
    const float* x      = (const float*)d_in[0];
    const float* values = (const float*)d_in[1];
    const float* weight = (const float*)d_in[2];
    const float* bias   = (const float*)d_in[3];
    const int*   row    = (const int*)d_in[4];
    const int*   col    = (const int*)d_in[5];
    const int*   sp     = (const int*)d_in[6];
    float*       out    = (float*)d_out;

    char* ws = (char*)d_ws;
    size_t off = 0;
    unsigned short* pooled  = (unsigned short*)(ws + off); off += (size_t)B * N_OUT * C * 2;      // 57,344,000
    unsigned short* packedW = (unsigned short*)(ws + off); off += (size_t)KB * 4 * 64 * 8 * 2;    // 73,728
    int*   offs   = (int*)(ws + off); off += ((size_t)(N_OUT + 1) * 4 + 124) / 128 * 128;
    int*   cursor = (int*)(ws + off); off += (size_t)N_OUT * 4 + 128;
    int*   cnt    = (int*)(ws + off); off += (size_t)N_OUT * 4 + 128;
    int*   ecol   = (int*)(ws + off); off += (size_t)NNZ * 4;
    float* eval   = (float*)(ws + off); off += (size_t)NNZ * 4;

    // CSR build (cnt must start at zero; ws is poisoned each call).
    (void)hipMemsetAsync(cnt, 0, (size_t)N_OUT * 4, stream);
    hist_kernel <<<(NNZ + 255) / 256, 256, 0, stream>>>(row, cnt);
    scan_kernel <<<1, 1024, 0, stream>>>(cnt, offs, cursor);
    place_kernel<<<(NNZ + 255) / 256, 256, 0, stream>>>(row, col, values, cursor, ecol, eval);

    // Pack weight into MFMA B-fragment order (independent of CSR chain).
    packw_kernel<<<KB, 256, 0, stream>>>(weight, packedW);

    // Pool into bf16 (one row per wave, all 16 batches, float4 loads).
    pool_kernel<<<N_OUT / 4, 256, 0, stream>>>(x, ecol, eval, offs, pooled);

    // Gathered GEMM + bias + ELU (XCD-pinned by batch, software-pipelined).
    spiral_mfma<<<B * MT, 256, 0, stream>>>(pooled,
        reinterpret_cast<const bf16x8*>(packedW), sp, bias, out);
}